// Round 3
// baseline (270.081 us; speedup 1.0000x reference)
//
#include <hip/hip_runtime.h>

// out[n,o,j,i] = sum_{a,b} inp[n,2,i+a,j+b] * kt[o,a,b]
//   inp: (32,3,224,224) f32, kt: (64,5,5) f32, out: (32,64,220,220) f32
//
// R2 theory: R0/R1 ran at ~3.0 TB/s effective write BW (fill kernel: 6.9)
// because each block interleaved 64 write streams at 193,600B stride.
// This version makes the store address monotone in (block, thread) order —
// grid = (f-chunk, o, n); each block writes ONE contiguous 4KB span of a
// single (n,o) plane. Input slab is staged transposed in LDS so each lane's
// 8-row window is two aligned conflict-free ds_read_b128.

#define IMG    224
#define OHW    220
#define FLAT   (OHW * OHW)     // 48400
#define NOUT   64
#define KW     5
#define BLOCK  256
#define QPB    (BLOCK * 4)     // outputs per block = 1024
#define NBX    48              // ceil(48400 / 1024)
#define COLS   10              // staged input columns (<=6 output cols + 4 halo)
#define PR     228             // transposed slab pitch (words); 228%4==0 -> aligned b128,
                               // 228%32==4 -> conflict-free compute reads
#define SLAB   (COLS * PR)     // 2280 floats = 9120 B

__global__ __launch_bounds__(BLOCK, 4)
void ConvolutionalLayer_88742614270062_kernel(const float* __restrict__ inp,
                                              const float* __restrict__ kt,
                                              float* __restrict__ out) {
    __shared__ float s[SLAB];   // s[c*PR + r]: column-major (transposed) slab

    const int n   = blockIdx.z;
    const int o   = blockIdx.y;
    const int f0  = blockIdx.x * QPB;       // first flat output index of block
    const int jlo = f0 / OHW;               // first output column touched

    // channel 2 of image n
    const float* __restrict__ xb = inp + ((size_t)(n * 3 + 2)) * (IMG * IMG);

    // Stage 224 rows x 10 cols, transposed. Guard right edge (cols >= 224 -> 0,
    // only ever touched by masked threads / unused halo).
    for (int idx = threadIdx.x; idx < IMG * COLS; idx += BLOCK) {
        int r   = idx / COLS;               // 0..223
        int c   = idx - r * COLS;           // 0..9
        int col = jlo + c;
        s[c * PR + r] = (col < IMG) ? xb[r * IMG + col] : 0.0f;
    }
    __syncthreads();

    const int f      = f0 + (int)threadIdx.x * 4;   // this thread's first output
    const bool live  = (f < FLAT);
    const int  fc    = live ? f : (FLAT - 4);        // clamp for safe LDS reads
    const int  j     = fc / OHW;
    const int  i4    = fc - j * OHW;                 // multiple of 4 (220 % 4 == 0)
    const int  cj    = j - jlo;                      // 0..5

    // Each lane: 5 columns x 8 rows window, two aligned ds_read_b128 per column.
    float w8[KW][8];
#pragma unroll
    for (int b = 0; b < KW; ++b) {
        const float4* p = reinterpret_cast<const float4*>(&s[(cj + b) * PR + i4]);
        float4 lo = p[0];
        float4 hi = p[1];
        w8[b][0] = lo.x; w8[b][1] = lo.y; w8[b][2] = lo.z; w8[b][3] = lo.w;
        w8[b][4] = hi.x; w8[b][5] = hi.y; w8[b][6] = hi.z; w8[b][7] = hi.w;
    }

    // Weights: o is blockIdx.y -> wave-uniform -> scalar loads.
    const float* __restrict__ wk = kt + o * (KW * KW);

    float a0 = 0.f, a1 = 0.f, a2 = 0.f, a3 = 0.f;
#pragma unroll
    for (int a = 0; a < KW; ++a) {
#pragma unroll
        for (int b = 0; b < KW; ++b) {
            float w = wk[a * KW + b];
            a0 = fmaf(w, w8[b][a    ], a0);
            a1 = fmaf(w, w8[b][a + 1], a1);
            a2 = fmaf(w, w8[b][a + 2], a2);
            a3 = fmaf(w, w8[b][a + 3], a3);
        }
    }

    if (live) {
        float* __restrict__ op = out + ((size_t)(n * NOUT + o)) * FLAT + f;
        *reinterpret_cast<float4*>(op) = make_float4(a0, a1, a2, a3);
    }
}

extern "C" void kernel_launch(void* const* d_in, const int* in_sizes, int n_in,
                              void* d_out, int out_size, void* d_ws, size_t ws_size,
                              hipStream_t stream) {
    const float* inp = (const float*)d_in[0];   // (32,3,224,224)
    const float* kt  = (const float*)d_in[1];   // (64,5,5)
    float* out       = (float*)d_out;           // (32,64,220,220)

    dim3 grid(NBX, NOUT, 32);                   // 48 x 64 x 32 blocks
    ConvolutionalLayer_88742614270062_kernel<<<grid, BLOCK, 0, stream>>>(inp, kt, out);
}

// Round 5
// 85.808 us; speedup vs baseline: 3.1475x; 3.1475x over previous
//
#include <hip/hip_runtime.h>

// out[n,o,j,i] = sum_{a,b} inp[n,2,i+a,j+b] * kt[o,a,b]
//   inp: (32,3,224,224) f32, kt: (64,5,5) f32, out: (32,64,220,220) f32
//
// R4 = R3 with the nontemporal store fixed to use a native clang ext_vector
// (the builtin rejects HIP_vector_type structs). Theory unchanged:
// - stage slab once per block, amortized over 8 output channels
// - nontemporal dwordx4 stores -> writeback ~program order, testing the
//   L2-hash-eviction-order theory for the 3 TB/s write ceiling seen in R0/R1.

#define IMG    224
#define OHW    220
#define FLAT   (OHW * OHW)     // 48400
#define NOUT   64
#define KW     5
#define BLOCK  256
#define QPB    (BLOCK * 4)     // outputs per (block, channel) = 1024
#define NBX    48              // ceil(48400 / 1024)
#define OG     8               // channels per block
#define COLS   10              // staged input columns (<=6 output cols + 4 halo)
#define PR     228             // transposed slab pitch (words), %4==0 for b128
#define SLAB   (COLS * PR)     // 2280 floats = 9120 B

typedef float floatx4 __attribute__((ext_vector_type(4)));

__global__ __launch_bounds__(BLOCK, 4)
void ConvolutionalLayer_88742614270062_kernel(const float* __restrict__ inp,
                                              const float* __restrict__ kt,
                                              float* __restrict__ out) {
    __shared__ float s[SLAB];   // s[c*PR + r]: transposed slab

    const int n   = blockIdx.z;
    const int og  = blockIdx.y * OG;        // first channel of this block
    const int f0  = blockIdx.x * QPB;       // first flat output index
    const int jlo = f0 / OHW;               // first output column touched

    const float* __restrict__ xb = inp + ((size_t)(n * 3 + 2)) * (IMG * IMG);

    // Stage once per block: 224 rows x 10 cols, transposed, right edge guarded.
    for (int idx = threadIdx.x; idx < IMG * COLS; idx += BLOCK) {
        int r   = idx / COLS;
        int c   = idx - r * COLS;
        int col = jlo + c;
        s[c * PR + r] = (col < IMG) ? xb[r * IMG + col] : 0.0f;
    }
    __syncthreads();

    const int  f    = f0 + (int)threadIdx.x * 4;
    const bool live = (f < FLAT);
    const int  fc   = live ? f : (FLAT - 4);    // clamp for safe LDS reads
    const int  j    = fc / OHW;
    const int  i4   = fc - j * OHW;             // multiple of 4
    const int  cj   = j - jlo;                  // 0..5

    // 5 cols x 8 rows window: two aligned conflict-free ds_read_b128 per col.
    float w8[KW][8];
#pragma unroll
    for (int b = 0; b < KW; ++b) {
        const floatx4* p = reinterpret_cast<const floatx4*>(&s[(cj + b) * PR + i4]);
        floatx4 lo = p[0];
        floatx4 hi = p[1];
        w8[b][0] = lo.x; w8[b][1] = lo.y; w8[b][2] = lo.z; w8[b][3] = lo.w;
        w8[b][4] = hi.x; w8[b][5] = hi.y; w8[b][6] = hi.z; w8[b][7] = hi.w;
    }

    // Weights: og wave-uniform -> scalar loads from kt.
    const float* __restrict__ wk = kt + og * (KW * KW);
    float* __restrict__ op = out + ((size_t)(n * NOUT + og)) * FLAT + f;

#pragma unroll
    for (int oc = 0; oc < OG; ++oc) {
        float a0 = 0.f, a1 = 0.f, a2 = 0.f, a3 = 0.f;
#pragma unroll
        for (int a = 0; a < KW; ++a) {
#pragma unroll
            for (int b = 0; b < KW; ++b) {
                float w = wk[oc * (KW * KW) + a * KW + b];
                a0 = fmaf(w, w8[b][a    ], a0);
                a1 = fmaf(w, w8[b][a + 1], a1);
                a2 = fmaf(w, w8[b][a + 2], a2);
                a3 = fmaf(w, w8[b][a + 3], a3);
            }
        }
        if (live) {
            floatx4 v = { a0, a1, a2, a3 };
            __builtin_nontemporal_store(v,
                reinterpret_cast<floatx4*>(op + (size_t)oc * FLAT));
        }
    }
}

extern "C" void kernel_launch(void* const* d_in, const int* in_sizes, int n_in,
                              void* d_out, int out_size, void* d_ws, size_t ws_size,
                              hipStream_t stream) {
    const float* inp = (const float*)d_in[0];   // (32,3,224,224)
    const float* kt  = (const float*)d_in[1];   // (64,5,5)
    float* out       = (float*)d_out;           // (32,64,220,220)

    dim3 grid(NBX, NOUT / OG, 32);              // 48 x 8 x 32 blocks
    ConvolutionalLayer_88742614270062_kernel<<<grid, BLOCK, 0, stream>>>(inp, kt, out);
}